// Round 5
// baseline (231.217 us; speedup 1.0000x reference)
//
#include <hip/hip_runtime.h>
#include <hip/hip_bf16.h>

typedef __bf16 bf16x8 __attribute__((ext_vector_type(8)));
typedef float  f32x4  __attribute__((ext_vector_type(4)));
typedef unsigned short u16;
typedef unsigned int   u32;

#define NBLK 256

__device__ __forceinline__ u16 f2b(float x) {
  __bf16 b = (__bf16)x;
  return __builtin_bit_cast(u16, b);
}

__device__ __forceinline__ void gload_lds16(const u16* g, u16* l) {
  __builtin_amdgcn_global_load_lds(
      (const __attribute__((address_space(1))) void*)g,
      (__attribute__((address_space(3))) void*)l, 16, 0, 0);
}

// device-scope grid barrier (requires all NBLK blocks co-resident: 256 blocks,
// 64KB LDS, 256 thr -> 1 block/CU on 256 CUs)
__device__ __forceinline__ void grid_barrier(u32* cnt, int idx) {
  __threadfence();            // release: flush this block's writes device-wide
  __syncthreads();
  if (threadIdx.x == 0) {
    atomicAdd(&cnt[idx * 16], 1u);
    while (__hip_atomic_load(&cnt[idx * 16], __ATOMIC_RELAXED,
                             __HIP_MEMORY_SCOPE_AGENT) < NBLK) {
      __builtin_amdgcn_s_sleep(1);
    }
  }
  __syncthreads();
  __threadfence();            // acquire: invalidate stale L1/L2 views
}

__global__ void zero_cnt_kernel(u32* cnt) {
  if (threadIdx.x < 64) cnt[threadIdx.x] = 0;
}

// ---------------- GEMM tile: C[128,128] += A[M,K] * Bt[N,K]^T ----------------
// Round-3 proven 2-phase core: dbuf LDS, prefetch before compute, __syncthreads.
template <int OUTF32>
__device__ __forceinline__ void gemm_tile(
    const u16* __restrict__ A, const u16* __restrict__ Bt, void* __restrict__ C,
    int N, int K, int row0, int col0,
    u16* As0, u16* As1, u16* Bs0, u16* Bs1)
{
  const int tid = threadIdx.x;
  const int wave = tid >> 6, lane = tid & 63;
  const int wm = wave >> 1, wn = wave & 1;

  f32x4 acc[4][4] = {};

  const int srow = lane >> 3, sslot = lane & 7;
  const int scol = ((sslot ^ srow) << 3);  // pre-swizzled source col

  const u16* gA = A + (size_t)(row0 + (wave << 5) + srow) * K + scol;
  const u16* gB = Bt + (size_t)(col0 + (wave << 5) + srow) * K + scol;

#define STAGE(as, bs, k0) do {                                           \
    _Pragma("unroll")                                                    \
    for (int i_ = 0; i_ < 4; ++i_) {                                     \
      int rb_ = (wave << 5) + (i_ << 3);                                 \
      gload_lds16(gA + (size_t)(i_ << 3) * K + (k0), (as) + (rb_ << 6)); \
      gload_lds16(gB + (size_t)(i_ << 3) * K + (k0), (bs) + (rb_ << 6)); \
    } } while (0)

  STAGE(As0, Bs0, 0);
  __syncthreads();

  u16 *asc = As0, *bsc = Bs0, *asn = As1, *bsn = Bs1;
  for (int k0 = 0; k0 < K; k0 += 64) {
    if (k0 + 64 < K) STAGE(asn, bsn, k0 + 64);   // prefetch flies under MFMA
#pragma unroll
    for (int kk = 0; kk < 2; ++kk) {
      bf16x8 af[4], bfr[4];
      int colb = (kk << 6) + ((lane >> 4) << 4);
#pragma unroll
      for (int m = 0; m < 4; ++m) {
        int r = (wm << 6) + (m << 4) + (lane & 15);
        af[m] = *(const bf16x8*)((const char*)asc + (r << 7) + (colb ^ ((r & 7) << 4)));
      }
#pragma unroll
      for (int n = 0; n < 4; ++n) {
        int r = (wn << 6) + (n << 4) + (lane & 15);
        bfr[n] = *(const bf16x8*)((const char*)bsc + (r << 7) + (colb ^ ((r & 7) << 4)));
      }
#pragma unroll
      for (int m = 0; m < 4; ++m)
#pragma unroll
        for (int n = 0; n < 4; ++n)
          acc[m][n] = __builtin_amdgcn_mfma_f32_16x16x32_bf16(af[m], bfr[n], acc[m][n], 0, 0, 0);
    }
    __syncthreads();
    u16* t_;
    t_ = asc; asc = asn; asn = t_;
    t_ = bsc; bsc = bsn; bsn = t_;
  }
#undef STAGE

  const int crow = (lane >> 4) << 2;
  const int ccol = lane & 15;
#pragma unroll
  for (int m = 0; m < 4; ++m) {
#pragma unroll
    for (int n = 0; n < 4; ++n) {
      int r = row0 + (wm << 6) + (m << 4) + crow;
      int c = col0 + (wn << 6) + (n << 4) + ccol;
#pragma unroll
      for (int reg = 0; reg < 4; ++reg) {
        if (OUTF32) ((float*)C)[(size_t)(r + reg) * N + c] = acc[m][n][reg];
        else        ((u16*)C)[(size_t)(r + reg) * N + c] = f2b(acc[m][n][reg]);
      }
    }
  }
}

// ---------------- attention tile (one jt/h/b) --------------------------------
#define VTP 56
#define PLP 72
__device__ __forceinline__ void attn_tile(
    const u16* __restrict__ Qp, const u16* __restrict__ Kp,
    const u16* __restrict__ Vp, u16* __restrict__ Ob,
    int jt, int h, int b, u16* Ql, u16* Kl, u16* Vt, u16* Pl)
{
  const int j0 = jt << 6;
  const int kbase = (j0 - 124) >> 2;
  const int tid = threadIdx.x;
  const int wave = tid >> 6, lane = tid & 63;

  const int srow = lane >> 3, sslot = lane & 7;
  const int scol = ((sslot ^ srow) << 3);
  for (int g = wave; g < 8; g += 4) {
    int r = (g << 3) + srow;
    const u16* ga = Qp + (((size_t)(b * 2048 + j0 + r)) << 10) + (h << 6) + scol;
    gload_lds16(ga, &Ql[g << 9]);
  }
  for (int g = wave; g < 6; g += 4) {
    int r = (g << 3) + srow;
    int key = kbase + r;
    key = key < 0 ? 0 : (key > 511 ? 511 : key);
    const u16* gk = Kp + (((size_t)(b * 512 + key)) << 10) + (h << 6) + scol;
    gload_lds16(gk, &Kl[g << 9]);
  }
  for (int idx = tid; idx < 48 * 8; idx += 256) {
    int row = idx >> 3, seg = idx & 7;
    int key = kbase + row;
    key = key < 0 ? 0 : (key > 511 ? 511 : key);
    uint4 x = *(const uint4*)(Vp + (((size_t)(b * 512 + key)) << 10) + (h << 6) + (seg << 3));
    int d0 = seg << 3;
    Vt[(d0 + 0) * VTP + row] = (u16)(x.x);
    Vt[(d0 + 1) * VTP + row] = (u16)(x.x >> 16);
    Vt[(d0 + 2) * VTP + row] = (u16)(x.y);
    Vt[(d0 + 3) * VTP + row] = (u16)(x.y >> 16);
    Vt[(d0 + 4) * VTP + row] = (u16)(x.z);
    Vt[(d0 + 5) * VTP + row] = (u16)(x.z >> 16);
    Vt[(d0 + 6) * VTP + row] = (u16)(x.w);
    Vt[(d0 + 7) * VTP + row] = (u16)(x.w >> 16);
  }
  if (tid < 64) *(uint4*)&Vt[tid * VTP + 48] = make_uint4(0, 0, 0, 0);
  else if (tid < 72) *(uint4*)&Vt[64 * VTP + ((tid - 64) << 3)] = make_uint4(0, 0, 0, 0);
  __syncthreads();

  f32x4 sacc[3] = {};
  const int frow_a = (wave << 4) + (lane & 15);
#pragma unroll
  for (int kk = 0; kk < 2; ++kk) {
    int colb = (kk << 6) + ((lane >> 4) << 4);
    bf16x8 aq = *(const bf16x8*)((const char*)Ql + (frow_a << 7) + (colb ^ ((frow_a & 7) << 4)));
#pragma unroll
    for (int nt = 0; nt < 3; ++nt) {
      int rk = (nt << 4) + (lane & 15);
      bf16x8 bk = *(const bf16x8*)((const char*)Kl + (rk << 7) + (colb ^ ((rk & 7) << 4)));
      sacc[nt] = __builtin_amdgcn_mfma_f32_16x16x32_bf16(aq, bk, sacc[nt], 0, 0, 0);
    }
  }

  const int rof = (wave << 2) + (lane >> 4);
  const int cb0 = lane & 15;
  bool vld[3]; float sc[3][4];
#pragma unroll
  for (int nt = 0; nt < 3; ++nt) {
    int c = cb0 + (nt << 4);
    vld[nt] = ((unsigned)(c - rof) < 32u) && (kbase + c >= 0);
#pragma unroll
    for (int r = 0; r < 4; ++r) sc[nt][r] = sacc[nt][r] * 0.125f;
  }
  float mx[4], rs[4];
#pragma unroll
  for (int r = 0; r < 4; ++r) {
    float m = -3.0e38f;
#pragma unroll
    for (int nt = 0; nt < 3; ++nt) m = vld[nt] ? fmaxf(m, sc[nt][r]) : m;
    m = fmaxf(m, __shfl_xor(m, 1));
    m = fmaxf(m, __shfl_xor(m, 2));
    m = fmaxf(m, __shfl_xor(m, 4));
    m = fmaxf(m, __shfl_xor(m, 8));
    mx[r] = m;
  }
#pragma unroll
  for (int r = 0; r < 4; ++r) {
    float s = 0.f;
#pragma unroll
    for (int nt = 0; nt < 3; ++nt) {
      float e = vld[nt] ? __expf(sc[nt][r] - mx[r]) : 0.f;
      sc[nt][r] = e;
      s += e;
    }
    s += __shfl_xor(s, 1);
    s += __shfl_xor(s, 2);
    s += __shfl_xor(s, 4);
    s += __shfl_xor(s, 8);
    rs[r] = 1.f / s;
  }
#pragma unroll
  for (int r = 0; r < 4; ++r) {
    int jq = (wave << 4) + ((lane >> 4) << 2) + r;
#pragma unroll
    for (int nt = 0; nt < 3; ++nt)
      Pl[jq * PLP + cb0 + (nt << 4)] = f2b(sc[nt][r] * rs[r]);
    Pl[jq * PLP + 48 + cb0] = 0;
  }
  __syncthreads();

  f32x4 oacc[4] = {};
#pragma unroll
  for (int kk = 0; kk < 2; ++kk) {
    int koff = (kk << 5) + ((lane >> 4) << 3);
    bf16x8 ap = *(const bf16x8*)&Pl[frow_a * PLP + koff];
#pragma unroll
    for (int nt = 0; nt < 4; ++nt) {
      int dr = (nt << 4) + (lane & 15);
      bf16x8 bv = *(const bf16x8*)&Vt[dr * VTP + koff];
      oacc[nt] = __builtin_amdgcn_mfma_f32_16x16x32_bf16(ap, bv, oacc[nt], 0, 0, 0);
    }
  }

#pragma unroll
  for (int nt = 0; nt < 4; ++nt) {
    int d = (nt << 4) + (lane & 15);
#pragma unroll
    for (int r = 0; r < 4; ++r) {
      int jq = (wave << 4) + ((lane >> 4) << 2) + r;
      Ob[(((size_t)(b * 2048 + j0 + jq)) << 10) + (h << 6) + d] = f2b(oacc[nt][r]);
    }
  }
}

// ---------------- fused persistent kernel: prep | proj | attn | outproj ------
#define Q4 1048576   // 2*2048*1024 / 4
#define K4 262144    // 2*512*1024 / 4

union SharedU {
  struct { u16 As[2][8192]; u16 Bs[2][8192]; } g;              // 64 KB
  struct { u16 Ql[4096]; u16 Kl[3072]; u16 Vt[64 * VTP + 64]; u16 Pl[64 * PLP]; } a;
  float tp[32][33];
};

__global__ __launch_bounds__(256) void fused_kernel(
    const float* __restrict__ q, const float* __restrict__ k, const float* __restrict__ v,
    const float* __restrict__ W0, const float* __restrict__ W1,
    const float* __restrict__ W2, const float* __restrict__ W3,
    float* __restrict__ out, char* __restrict__ ws)
{
  __shared__ SharedU sh;
  const size_t MB = 1u << 20;
  u16* qb  = (u16*)(ws + 0 * MB);    // P1 write, P2 read; reused as Ob in P3/P4
  u16* kb  = (u16*)(ws + 8 * MB);
  u16* vb  = (u16*)(ws + 10 * MB);
  u16* Wqt = (u16*)(ws + 12 * MB);
  u16* Wkt = (u16*)(ws + 14 * MB);
  u16* Wvt = (u16*)(ws + 16 * MB);
  u16* Wot = (u16*)(ws + 18 * MB);
  u16* Qp  = (u16*)(ws + 20 * MB);
  u16* Kp  = (u16*)(ws + 28 * MB);   // Kp||Vp contiguous
  u16* Vp  = (u16*)(ws + 30 * MB);
  u16* Ob  = qb;                      // aliases qb (dead after P2)
  u32* cnt = (u32*)(ws + 32 * MB);

  const int bid = blockIdx.x;
  const int tid = threadIdx.x;
  const int gtid = bid * 256 + tid;
  const int NT = NBLK * 256;

  // ===== P1: cvt q/k/v f32->bf16 (batched x4) + transpose/cvt weights =====
  {
    const float4* s4 = (const float4*)q;
    ushort4* d4 = (ushort4*)qb;
    for (int base = gtid; base < Q4; base += NT * 4) {
      float4 x0 = s4[base], x1 = s4[base + NT], x2 = s4[base + 2 * NT], x3 = s4[base + 3 * NT];
      ushort4 r0, r1, r2, r3;
      r0.x = f2b(x0.x); r0.y = f2b(x0.y); r0.z = f2b(x0.z); r0.w = f2b(x0.w);
      r1.x = f2b(x1.x); r1.y = f2b(x1.y); r1.z = f2b(x1.z); r1.w = f2b(x1.w);
      r2.x = f2b(x2.x); r2.y = f2b(x2.y); r2.z = f2b(x2.z); r2.w = f2b(x2.w);
      r3.x = f2b(x3.x); r3.y = f2b(x3.y); r3.z = f2b(x3.z); r3.w = f2b(x3.w);
      d4[base] = r0; d4[base + NT] = r1; d4[base + 2 * NT] = r2; d4[base + 3 * NT] = r3;
    }
    const float4* sk = (const float4*)k;
    const float4* sv = (const float4*)v;
    ushort4* dk = (ushort4*)kb;
    ushort4* dv = (ushort4*)vb;
    for (int base = gtid; base < K4; base += NT * 2) {
      float4 x0 = sk[base], x1 = sk[base + NT], x2 = sv[base], x3 = sv[base + NT];
      ushort4 r0, r1, r2, r3;
      r0.x = f2b(x0.x); r0.y = f2b(x0.y); r0.z = f2b(x0.z); r0.w = f2b(x0.w);
      r1.x = f2b(x1.x); r1.y = f2b(x1.y); r1.z = f2b(x1.z); r1.w = f2b(x1.w);
      r2.x = f2b(x2.x); r2.y = f2b(x2.y); r2.z = f2b(x2.z); r2.w = f2b(x2.w);
      r3.x = f2b(x3.x); r3.y = f2b(x3.y); r3.z = f2b(x3.z); r3.w = f2b(x3.w);
      dk[base] = r0; dk[base + NT] = r1; dv[base] = r2; dv[base + NT] = r3;
    }
    // weight transpose: 4096 tiles of 32x32, 16 per block
    int tx = tid & 31, ty = tid >> 5;
    for (int tt = bid; tt < 4096; tt += NBLK) {
      int z = tt >> 10, rem = tt & 1023;
      const float* W = (z == 0) ? W0 : (z == 1) ? W1 : (z == 2) ? W2 : W3;
      u16* T = (z == 0) ? Wqt : (z == 1) ? Wkt : (z == 2) ? Wvt : Wot;
      int c0 = (rem & 31) << 5, r0 = (rem >> 5) << 5;
      __syncthreads();
#pragma unroll
      for (int i = 0; i < 4; ++i)
        sh.tp[ty + i * 8][tx] = W[(size_t)(r0 + ty + i * 8) * 1024 + c0 + tx];
      __syncthreads();
#pragma unroll
      for (int i = 0; i < 4; ++i)
        T[(size_t)(c0 + ty + i * 8) * 1024 + r0 + tx] = f2b(sh.tp[tx][ty + i * 8]);
    }
  }
  grid_barrier(cnt, 0);

  // ===== P2: projections (384 tiles: 256 Q + 128 KV) =====
  for (int t = bid; t < 384; t += NBLK) {
    __syncthreads();
    const u16 *A, *Bt; u16* C; int row0, col0;
    if (t < 256) {
      A = qb; Bt = Wqt; C = Qp;
      row0 = (t >> 3) << 7; col0 = (t & 7) << 7;
    } else {
      int t2 = t - 256;
      row0 = (t2 >> 3) << 7; col0 = (t2 & 7) << 7;
      A = kb; C = Kp;
      Bt = (row0 >= 1024) ? Wvt : Wkt;
    }
    gemm_tile<0>(A, Bt, C, 1024, 1024, row0, col0,
                 sh.g.As[0], sh.g.As[1], sh.g.Bs[0], sh.g.Bs[1]);
  }
  grid_barrier(cnt, 1);

  // ===== P3: attention (1024 tiles, 4 per block) =====
  for (int t = bid; t < 1024; t += NBLK) {
    __syncthreads();
    int jt = t & 31, h = (t >> 5) & 15, b = t >> 9;
    attn_tile(Qp, Kp, Vp, Ob, jt, h, b, sh.a.Ql, sh.a.Kl, sh.a.Vt, sh.a.Pl);
  }
  grid_barrier(cnt, 2);

  // ===== P4: output projection (256 tiles, 1 per block, f32 out) =====
  {
    int t = bid;
    int row0 = (t >> 3) << 7, col0 = (t & 7) << 7;
    gemm_tile<1>(Ob, Wot, out, 1024, 1024, row0, col0,
                 sh.g.As[0], sh.g.As[1], sh.g.Bs[0], sh.g.Bs[1]);
  }
}

extern "C" void kernel_launch(void* const* d_in, const int* in_sizes, int n_in,
                              void* d_out, int out_size, void* d_ws, size_t ws_size,
                              hipStream_t stream) {
  const float* q  = (const float*)d_in[0];
  const float* k  = (const float*)d_in[1];
  const float* v  = (const float*)d_in[2];
  const float* Wq = (const float*)d_in[3];
  const float* Wk = (const float*)d_in[4];
  const float* Wv = (const float*)d_in[5];
  const float* Wo = (const float*)d_in[6];

  char* ws = (char*)d_ws;
  u32* cnt = (u32*)(ws + (size_t)(32u << 20));

  zero_cnt_kernel<<<1, 64, 0, stream>>>(cnt);
  fused_kernel<<<NBLK, 256, 0, stream>>>(q, k, v, Wq, Wk, Wv, Wo, (float*)d_out, ws);
}

// Round 6
// 61.605 us; speedup vs baseline: 3.7532x; 3.7532x over previous
//
#include <hip/hip_runtime.h>
#include <hip/hip_bf16.h>

typedef __bf16 bf16x8 __attribute__((ext_vector_type(8)));
typedef float  f32x4  __attribute__((ext_vector_type(4)));
typedef unsigned short u16;
typedef unsigned int   u32;

__device__ __forceinline__ u16 f2b(float x) {
  __bf16 b = (__bf16)x;
  return __builtin_bit_cast(u16, b);
}

__device__ __forceinline__ void gload_lds16(const u16* g, u16* l) {
  __builtin_amdgcn_global_load_lds(
      (const __attribute__((address_space(1))) void*)g,
      (__attribute__((address_space(3))) void*)l, 16, 0, 0);
}

// ---------------- prep: cvt q/k/v f32->bf16  +  transpose+cvt 4 weights ------
#define Q4 1048576   // 2*2048*1024/4
#define K4 262144    // 2*512*1024/4
#define CVT_BLOCKS 6144
__global__ __launch_bounds__(256) void prep_kernel(
    const float* __restrict__ q, const float* __restrict__ k, const float* __restrict__ v,
    u16* __restrict__ qb, u16* __restrict__ kb, u16* __restrict__ vb,
    const float* __restrict__ W0, const float* __restrict__ W1,
    const float* __restrict__ W2, const float* __restrict__ W3,
    u16* __restrict__ T0, u16* __restrict__ T1, u16* __restrict__ T2, u16* __restrict__ T3)
{
  __shared__ float tile[32][33];
  int bid = blockIdx.x;
  if (bid < CVT_BLOCKS) {
    int i = bid * 256 + threadIdx.x;
    const float* src; u16* dst; int off;
    if (i < Q4)            { src = q; dst = qb; off = i; }
    else if (i < Q4 + K4)  { src = k; dst = kb; off = i - Q4; }
    else                   { src = v; dst = vb; off = i - Q4 - K4; }
    float4 x = ((const float4*)src)[off];
    ushort4 r;
    r.x = f2b(x.x); r.y = f2b(x.y); r.z = f2b(x.z); r.w = f2b(x.w);
    ((ushort4*)dst)[off] = r;
  } else {
    int t = bid - CVT_BLOCKS;
    int z = t >> 10, rem = t & 1023;
    const float* W = (z == 0) ? W0 : (z == 1) ? W1 : (z == 2) ? W2 : W3;
    u16* T = (z == 0) ? T0 : (z == 1) ? T1 : (z == 2) ? T2 : T3;
    int tx = threadIdx.x & 31, ty = threadIdx.x >> 5;
    int c0 = (rem & 31) << 5, r0 = (rem >> 5) << 5;
#pragma unroll
    for (int i = 0; i < 4; ++i)
      tile[ty + i * 8][tx] = W[(size_t)(r0 + ty + i * 8) * 1024 + c0 + tx];
    __syncthreads();
#pragma unroll
    for (int i = 0; i < 4; ++i)
      T[(size_t)(c0 + ty + i * 8) * 1024 + r0 + tx] = f2b(tile[tx][ty + i * 8]);
  }
}

// ---------------- bf16 MFMA GEMM core: 128x64 tile = A[M,K] * Bt[N,K]^T ------
// BM=128, BN=64, BK=64, 256 threads (4 waves, 2x2), wave tile 64x32 (4x2 frags).
// Double-buffered LDS (48 KB) -> 3 blocks/CU: block-level TLP hides the
// prefetch latency that the 2-phase __syncthreads drain exposes.
template <int OUTF32>
__device__ __forceinline__ void gemm_core(
    const u16* __restrict__ A, const u16* __restrict__ Bt, void* __restrict__ C,
    int N, int K, int row0, int col0,
    u16* As0, u16* As1, u16* Bs0, u16* Bs1)
{
  const int tid = threadIdx.x;
  const int wave = tid >> 6, lane = tid & 63;
  const int wm = wave >> 1, wn = wave & 1;

  f32x4 acc[4][2] = {};

  const int srow = lane >> 3, sslot = lane & 7;
  const int scol = ((sslot ^ srow) << 3);  // pre-swizzled source col

  const u16* gA = A + (size_t)(row0 + (wave << 5) + srow) * K + scol;   // 32 A-rows/wave
  const u16* gB = Bt + (size_t)(col0 + (wave << 4) + srow) * K + scol;  // 16 B-rows/wave

#define STAGE(as, bs, k0) do {                                             \
    _Pragma("unroll")                                                      \
    for (int i_ = 0; i_ < 4; ++i_) {                                       \
      int rb_ = (wave << 5) + (i_ << 3);                                   \
      gload_lds16(gA + (size_t)(i_ << 3) * K + (k0), (as) + (rb_ << 6));   \
    }                                                                      \
    _Pragma("unroll")                                                      \
    for (int i_ = 0; i_ < 2; ++i_) {                                       \
      int rb_ = (wave << 4) + (i_ << 3);                                   \
      gload_lds16(gB + (size_t)(i_ << 3) * K + (k0), (bs) + (rb_ << 6));   \
    } } while (0)

  STAGE(As0, Bs0, 0);
  __syncthreads();

  u16 *asc = As0, *bsc = Bs0, *asn = As1, *bsn = Bs1;
  for (int k0 = 0; k0 < K; k0 += 64) {
    if (k0 + 64 < K) STAGE(asn, bsn, k0 + 64);   // prefetch flies under MFMA
#pragma unroll
    for (int kk = 0; kk < 2; ++kk) {
      bf16x8 af[4], bfr[2];
      int colb = (kk << 6) + ((lane >> 4) << 4);  // byte col within 128B row
#pragma unroll
      for (int m = 0; m < 4; ++m) {
        int r = (wm << 6) + (m << 4) + (lane & 15);
        af[m] = *(const bf16x8*)((const char*)asc + (r << 7) + (colb ^ ((r & 7) << 4)));
      }
#pragma unroll
      for (int n = 0; n < 2; ++n) {
        int r = (wn << 5) + (n << 4) + (lane & 15);
        bfr[n] = *(const bf16x8*)((const char*)bsc + (r << 7) + (colb ^ ((r & 7) << 4)));
      }
#pragma unroll
      for (int m = 0; m < 4; ++m)
#pragma unroll
        for (int n = 0; n < 2; ++n)
          acc[m][n] = __builtin_amdgcn_mfma_f32_16x16x32_bf16(af[m], bfr[n], acc[m][n], 0, 0, 0);
    }
    __syncthreads();
    u16* t_;
    t_ = asc; asc = asn; asn = t_;
    t_ = bsc; bsc = bsn; bsn = t_;
  }
#undef STAGE

  const int crow = (lane >> 4) << 2;
  const int ccol = lane & 15;
#pragma unroll
  for (int m = 0; m < 4; ++m) {
#pragma unroll
    for (int n = 0; n < 2; ++n) {
      int r = row0 + (wm << 6) + (m << 4) + crow;
      int c = col0 + (wn << 5) + (n << 4) + ccol;
#pragma unroll
      for (int reg = 0; reg < 4; ++reg) {
        if (OUTF32) ((float*)C)[(size_t)(r + reg) * N + c] = acc[m][n][reg];
        else        ((u16*)C)[(size_t)(r + reg) * N + c] = f2b(acc[m][n][reg]);
      }
    }
  }
}

// out projection (f32 out): 512 blocks of 128x64 tiles
template <int OUTF32>
__global__ __launch_bounds__(256, 3) void gemm_bt_kernel(
    const u16* __restrict__ A, const u16* __restrict__ Bt, void* __restrict__ C,
    int M, int N, int K)
{
  __shared__ u16 As[2][8192];
  __shared__ u16 Bs[2][4096];
  const int nbx = N >> 6;
  const int bx = blockIdx.x % nbx, by = blockIdx.x / nbx;
  gemm_core<OUTF32>(A, Bt, C, N, K, by << 7, bx << 6, As[0], As[1], Bs[0], Bs[1]);
}

// fused Q + K + V projections in one launch (768 blocks of 128x64 tiles)
__global__ __launch_bounds__(256, 3) void proj_kernel(
    const u16* __restrict__ qb, const u16* __restrict__ kvb,
    const u16* __restrict__ Wqt, const u16* __restrict__ Wkt, const u16* __restrict__ Wvt,
    u16* __restrict__ Qp, u16* __restrict__ KVp)
{
  __shared__ u16 As[2][8192];
  __shared__ u16 Bs[2][4096];
  int bid = blockIdx.x;
  const u16 *A, *Bt; u16* C; int row0, col0;
  if (bid < 512) {                       // Q projection: M=4096, 32x16 tiles
    A = qb; Bt = Wqt; C = Qp;
    row0 = (bid >> 4) << 7; col0 = (bid & 15) << 6;
  } else {                               // K/V projections: M=2048 (B switches at row 1024)
    int t = bid - 512;
    row0 = (t >> 4) << 7; col0 = (t & 15) << 6;
    A = kvb; C = KVp;
    Bt = (row0 >= 1024) ? Wvt : Wkt;
  }
  gemm_core<0>(A, Bt, C, 1024, 1024, row0, col0, As[0], As[1], Bs[0], Bs[1]);
}

// ---------------- strided-local attention (MFMA) ------------------------------
// Block = (64-query tile jt, head h, batch b). kbase = (j0-124)/4 (exact).
// Query jq attends slab cols [rof, rof+32), rof = jq>>2 in [0,16); valid iff kbase+c >= 0.
#define VTP 56   // Vt pitch (elems)
#define PLP 72   // Pl pitch (elems)
__global__ __launch_bounds__(256) void attn_kernel(
    const u16* __restrict__ Qp, const u16* __restrict__ Kp,
    const u16* __restrict__ Vp, u16* __restrict__ Ob)
{
  __shared__ u16 Ql[64 * 64];          // swizzled 128B rows
  __shared__ u16 Kl[48 * 64];          // swizzled 128B rows
  __shared__ u16 Vt[64 * VTP + 64];    // V^T [d][c] + zeroed tail
  __shared__ u16 Pl[64 * PLP];         // P [jq][c], cols 48..63 zeroed

  const int jt = blockIdx.x, h = blockIdx.y, b = blockIdx.z;
  const int j0 = jt << 6;
  const int kbase = (j0 - 124) >> 2;
  const int tid = threadIdx.x;
  const int wave = tid >> 6, lane = tid & 63;

  const int srow = lane >> 3, sslot = lane & 7;
  const int scol = ((sslot ^ srow) << 3);
  for (int g = wave; g < 8; g += 4) {
    int r = (g << 3) + srow;
    const u16* ga = Qp + (((size_t)(b * 2048 + j0 + r)) << 10) + (h << 6) + scol;
    gload_lds16(ga, &Ql[g << 9]);
  }
  for (int g = wave; g < 6; g += 4) {
    int r = (g << 3) + srow;
    int key = kbase + r;
    key = key < 0 ? 0 : (key > 511 ? 511 : key);
    const u16* gk = Kp + (((size_t)(b * 512 + key)) << 10) + (h << 6) + scol;
    gload_lds16(gk, &Kl[g << 9]);
  }
  for (int idx = tid; idx < 48 * 8; idx += 256) {
    int row = idx >> 3, seg = idx & 7;
    int key = kbase + row;
    key = key < 0 ? 0 : (key > 511 ? 511 : key);
    uint4 x = *(const uint4*)(Vp + (((size_t)(b * 512 + key)) << 10) + (h << 6) + (seg << 3));
    int d0 = seg << 3;
    Vt[(d0 + 0) * VTP + row] = (u16)(x.x);
    Vt[(d0 + 1) * VTP + row] = (u16)(x.x >> 16);
    Vt[(d0 + 2) * VTP + row] = (u16)(x.y);
    Vt[(d0 + 3) * VTP + row] = (u16)(x.y >> 16);
    Vt[(d0 + 4) * VTP + row] = (u16)(x.z);
    Vt[(d0 + 5) * VTP + row] = (u16)(x.z >> 16);
    Vt[(d0 + 6) * VTP + row] = (u16)(x.w);
    Vt[(d0 + 7) * VTP + row] = (u16)(x.w >> 16);
  }
  if (tid < 64) *(uint4*)&Vt[tid * VTP + 48] = make_uint4(0, 0, 0, 0);
  else if (tid < 72) *(uint4*)&Vt[64 * VTP + ((tid - 64) << 3)] = make_uint4(0, 0, 0, 0);
  __syncthreads();

  f32x4 sacc[3] = {};
  const int frow_a = (wave << 4) + (lane & 15);
#pragma unroll
  for (int kk = 0; kk < 2; ++kk) {
    int colb = (kk << 6) + ((lane >> 4) << 4);
    bf16x8 aq = *(const bf16x8*)((const char*)Ql + (frow_a << 7) + (colb ^ ((frow_a & 7) << 4)));
#pragma unroll
    for (int nt = 0; nt < 3; ++nt) {
      int rk = (nt << 4) + (lane & 15);
      bf16x8 bk = *(const bf16x8*)((const char*)Kl + (rk << 7) + (colb ^ ((rk & 7) << 4)));
      sacc[nt] = __builtin_amdgcn_mfma_f32_16x16x32_bf16(aq, bk, sacc[nt], 0, 0, 0);
    }
  }

  const int rof = (wave << 2) + (lane >> 4);
  const int cb0 = lane & 15;
  bool vld[3]; float sc[3][4];
#pragma unroll
  for (int nt = 0; nt < 3; ++nt) {
    int c = cb0 + (nt << 4);
    vld[nt] = ((unsigned)(c - rof) < 32u) && (kbase + c >= 0);
#pragma unroll
    for (int r = 0; r < 4; ++r) sc[nt][r] = sacc[nt][r] * 0.125f;
  }
  float mx[4], rs[4];
#pragma unroll
  for (int r = 0; r < 4; ++r) {
    float m = -3.0e38f;
#pragma unroll
    for (int nt = 0; nt < 3; ++nt) m = vld[nt] ? fmaxf(m, sc[nt][r]) : m;
    m = fmaxf(m, __shfl_xor(m, 1));
    m = fmaxf(m, __shfl_xor(m, 2));
    m = fmaxf(m, __shfl_xor(m, 4));
    m = fmaxf(m, __shfl_xor(m, 8));
    mx[r] = m;
  }
#pragma unroll
  for (int r = 0; r < 4; ++r) {
    float s = 0.f;
#pragma unroll
    for (int nt = 0; nt < 3; ++nt) {
      float e = vld[nt] ? __expf(sc[nt][r] - mx[r]) : 0.f;
      sc[nt][r] = e;
      s += e;
    }
    s += __shfl_xor(s, 1);
    s += __shfl_xor(s, 2);
    s += __shfl_xor(s, 4);
    s += __shfl_xor(s, 8);
    rs[r] = 1.f / s;
  }
#pragma unroll
  for (int r = 0; r < 4; ++r) {
    int jq = (wave << 4) + ((lane >> 4) << 2) + r;
#pragma unroll
    for (int nt = 0; nt < 3; ++nt)
      Pl[jq * PLP + cb0 + (nt << 4)] = f2b(sc[nt][r] * rs[r]);
    Pl[jq * PLP + 48 + cb0] = 0;
  }
  __syncthreads();

  f32x4 oacc[4] = {};
#pragma unroll
  for (int kk = 0; kk < 2; ++kk) {
    int koff = (kk << 5) + ((lane >> 4) << 3);
    bf16x8 ap = *(const bf16x8*)&Pl[frow_a * PLP + koff];
#pragma unroll
    for (int nt = 0; nt < 4; ++nt) {
      int dr = (nt << 4) + (lane & 15);
      bf16x8 bv = *(const bf16x8*)&Vt[dr * VTP + koff];
      oacc[nt] = __builtin_amdgcn_mfma_f32_16x16x32_bf16(ap, bv, oacc[nt], 0, 0, 0);
    }
  }

#pragma unroll
  for (int nt = 0; nt < 4; ++nt) {
    int d = (nt << 4) + (lane & 15);
#pragma unroll
    for (int r = 0; r < 4; ++r) {
      int jq = (wave << 4) + ((lane >> 4) << 2) + r;
      Ob[(((size_t)(b * 2048 + j0 + jq)) << 10) + (h << 6) + d] = f2b(oacc[nt][r]);
    }
  }
}

extern "C" void kernel_launch(void* const* d_in, const int* in_sizes, int n_in,
                              void* d_out, int out_size, void* d_ws, size_t ws_size,
                              hipStream_t stream) {
  const float* q  = (const float*)d_in[0];
  const float* k  = (const float*)d_in[1];
  const float* v  = (const float*)d_in[2];
  const float* Wq = (const float*)d_in[3];
  const float* Wk = (const float*)d_in[4];
  const float* Wv = (const float*)d_in[5];
  const float* Wo = (const float*)d_in[6];

  char* ws = (char*)d_ws;
  const size_t MB = 1u << 20;
  u16* qb  = (u16*)(ws + 0 * MB);    // 8 MB
  u16* kb  = (u16*)(ws + 8 * MB);    // 2 MB  (kb||vb contiguous)
  u16* vb  = (u16*)(ws + 10 * MB);   // 2 MB
  u16* Wqt = (u16*)(ws + 12 * MB);   // 2 MB
  u16* Wkt = (u16*)(ws + 14 * MB);
  u16* Wvt = (u16*)(ws + 16 * MB);
  u16* Wot = (u16*)(ws + 18 * MB);
  u16* Qp  = (u16*)(ws + 20 * MB);   // 8 MB
  u16* Kp  = (u16*)(ws + 28 * MB);   // 2 MB  (Kp||Vp contiguous)
  u16* Vp  = (u16*)(ws + 30 * MB);   // 2 MB
  u16* Ob  = (u16*)(ws + 32 * MB);   // 8 MB  (total 40 MB)

  // 1) prep: convert q/k/v to bf16 + transpose/convert the 4 weight matrices
  prep_kernel<<<CVT_BLOCKS + 4096, 256, 0, stream>>>(
      q, k, v, qb, kb, vb, Wq, Wk, Wv, Wo, Wqt, Wkt, Wvt, Wot);
  // 2) all three projections in one launch (768 x 128x64 tiles, 3 blocks/CU)
  proj_kernel<<<768, 256, 0, stream>>>(qb, kb, Wqt, Wkt, Wvt, Qp, Kp);
  // 3) attention (MFMA)
  attn_kernel<<<dim3(32, 16, 2), 256, 0, stream>>>(Qp, Kp, Vp, Ob);
  // 4) output projection (f32 out, 512 x 128x64 tiles, 2 blocks/CU)
  gemm_bt_kernel<1><<<512, 256, 0, stream>>>(Ob, Wot, d_out, 4096, 1024, 1024);
}

// Round 8
// 59.631 us; speedup vs baseline: 3.8775x; 1.0331x over previous
//
#include <hip/hip_runtime.h>
#include <hip/hip_bf16.h>

typedef __bf16 bf16x8 __attribute__((ext_vector_type(8)));
typedef float  f32x4  __attribute__((ext_vector_type(4)));
typedef unsigned short u16;
typedef unsigned int   u32;

__device__ __forceinline__ u16 f2b(float x) {
  __bf16 b = (__bf16)x;
  return __builtin_bit_cast(u16, b);
}

__device__ __forceinline__ void gload_lds16(const u16* g, u16* l) {
  __builtin_amdgcn_global_load_lds(
      (const __attribute__((address_space(1))) void*)g,
      (__attribute__((address_space(3))) void*)l, 16, 0, 0);
}

// pack 8 f32 -> 8 bf16, one ds_write_b128
__device__ __forceinline__ void cvt8_store(u16* dst, float4 a, float4 b) {
  union { u16 u[8]; uint4 v; } r;
  r.u[0] = f2b(a.x); r.u[1] = f2b(a.y); r.u[2] = f2b(a.z); r.u[3] = f2b(a.w);
  r.u[4] = f2b(b.x); r.u[5] = f2b(b.y); r.u[6] = f2b(b.z); r.u[7] = f2b(b.w);
  *(uint4*)dst = r.v;
}

// ---------------- prep: transpose + cvt the 4 weight matrices only -----------
__global__ __launch_bounds__(256) void prep_kernel(
    const float* __restrict__ W0, const float* __restrict__ W1,
    const float* __restrict__ W2, const float* __restrict__ W3,
    u16* __restrict__ T0, u16* __restrict__ T1, u16* __restrict__ T2, u16* __restrict__ T3)
{
  __shared__ float tile[32][33];
  int t = blockIdx.x;
  int z = t >> 10, rem = t & 1023;
  const float* W = (z == 0) ? W0 : (z == 1) ? W1 : (z == 2) ? W2 : W3;
  u16* T = (z == 0) ? T0 : (z == 1) ? T1 : (z == 2) ? T2 : T3;
  int tx = threadIdx.x & 31, ty = threadIdx.x >> 5;
  int c0 = (rem & 31) << 5, r0 = (rem >> 5) << 5;
#pragma unroll
  for (int i = 0; i < 4; ++i)
    tile[ty + i * 8][tx] = W[(size_t)(r0 + ty + i * 8) * 1024 + c0 + tx];
  __syncthreads();
#pragma unroll
  for (int i = 0; i < 4; ++i)
    T[(size_t)(c0 + ty + i * 8) * 1024 + r0 + tx] = f2b(tile[tx][ty + i * 8]);
}

// ---------------- shared GEMM pieces (R3-proven 128x128, 4 waves) ------------
__device__ __forceinline__ void compute_step(
    const u16* asc, const u16* bsc, int lane, int wm, int wn, f32x4 (&acc)[4][4])
{
#pragma unroll
  for (int kk = 0; kk < 2; ++kk) {
    bf16x8 af[4], bfr[4];
    int colb = (kk << 6) + ((lane >> 4) << 4);  // byte col within 128B row
#pragma unroll
    for (int m = 0; m < 4; ++m) {
      int r = (wm << 6) + (m << 4) + (lane & 15);
      af[m] = *(const bf16x8*)((const char*)asc + (r << 7) + (colb ^ ((r & 7) << 4)));
    }
#pragma unroll
    for (int n = 0; n < 4; ++n) {
      int r = (wn << 6) + (n << 4) + (lane & 15);
      bfr[n] = *(const bf16x8*)((const char*)bsc + (r << 7) + (colb ^ ((r & 7) << 4)));
    }
#pragma unroll
    for (int m = 0; m < 4; ++m)
#pragma unroll
      for (int n = 0; n < 4; ++n)
        acc[m][n] = __builtin_amdgcn_mfma_f32_16x16x32_bf16(af[m], bfr[n], acc[m][n], 0, 0, 0);
  }
}

__device__ __forceinline__ void stage_b(const u16* gB, u16* bs, int wave, int K, int k0) {
#pragma unroll
  for (int i = 0; i < 4; ++i) {
    int rb = (wave << 5) + (i << 3);
    gload_lds16(gB + (size_t)(i << 3) * K + k0, bs + (rb << 6));
  }
}

template <int OUTF32>
__device__ __forceinline__ void cwrite(
    void* C, int N, int row0, int col0, int lane, int wm, int wn, f32x4 (&acc)[4][4])
{
  const int crow = (lane >> 4) << 2;
  const int ccol = lane & 15;
#pragma unroll
  for (int m = 0; m < 4; ++m) {
#pragma unroll
    for (int n = 0; n < 4; ++n) {
      int r = row0 + (wm << 6) + (m << 4) + crow;
      int c = col0 + (wn << 6) + (n << 4) + ccol;
#pragma unroll
      for (int reg = 0; reg < 4; ++reg) {
        if (OUTF32) ((float*)C)[(size_t)(r + reg) * N + c] = acc[m][n][reg];
        else        ((u16*)C)[(size_t)(r + reg) * N + c] = f2b(acc[m][n][reg]);
      }
    }
  }
}

// ---------------- GEMM core, bf16 A via gload_lds (outproj) -----------------
template <int OUTF32>
__device__ __forceinline__ void gemm_core(
    const u16* __restrict__ A, const u16* __restrict__ Bt, void* __restrict__ C,
    int N, int K, int row0, int col0,
    u16* As0, u16* As1, u16* Bs0, u16* Bs1)
{
  const int tid = threadIdx.x;
  const int wave = tid >> 6, lane = tid & 63;
  const int wm = wave >> 1, wn = wave & 1;
  f32x4 acc[4][4] = {};

  const int srow = lane >> 3, sslot = lane & 7;
  const int scol = ((sslot ^ srow) << 3);  // pre-swizzled source col
  const u16* gA = A + (size_t)(row0 + (wave << 5) + srow) * K + scol;
  const u16* gB = Bt + (size_t)(col0 + (wave << 5) + srow) * K + scol;

  stage_b(gA, As0, wave, K, 0);
  stage_b(gB, Bs0, wave, K, 0);
  __syncthreads();

  u16 *asc = As0, *bsc = Bs0, *asn = As1, *bsn = Bs1;
  for (int k0 = 0; k0 < K; k0 += 64) {
    if (k0 + 64 < K) {
      stage_b(gA, asn, wave, K, k0 + 64);
      stage_b(gB, bsn, wave, K, k0 + 64);
    }
    compute_step(asc, bsc, lane, wm, wn, acc);
    __syncthreads();
    u16* t_;
    t_ = asc; asc = asn; asn = t_;
    t_ = bsc; bsc = bsn; bsn = t_;
  }
  cwrite<OUTF32>(C, N, row0, col0, lane, wm, wn, acc);
}

// ---------------- GEMM core, f32 A reg-staged + cvt (projections) ------------
__device__ __forceinline__ void gemm_core_f32a(
    const float* __restrict__ Af,    // pre-offset to row0 of this tile
    const u16* __restrict__ Bt, u16* __restrict__ C,
    int N, int K, int row0, int col0,
    u16* As0, u16* As1, u16* Bs0, u16* Bs1)
{
  const int tid = threadIdx.x;
  const int wave = tid >> 6, lane = tid & 63;
  const int wm = wave >> 1, wn = wave & 1;
  f32x4 acc[4][4] = {};

  const int srow = lane >> 3, sslot = lane & 7;
  const int scol = ((sslot ^ srow) << 3);
  const float* gAf = Af + (size_t)((wave << 5) + srow) * K + scol;
  const u16*  gB  = Bt + (size_t)(col0 + (wave << 5) + srow) * K + scol;
  const int awbase = (lane << 3);  // elems; +((wave*32+i*8)<<6) per sub-row

  float4 a0[4], a1[4];
  // prologue: tile 0
#pragma unroll
  for (int i = 0; i < 4; ++i) {
    const float* g = gAf + (size_t)(i << 3) * K;
    a0[i] = *(const float4*)g; a1[i] = *(const float4*)(g + 4);
  }
  stage_b(gB, Bs0, wave, K, 0);
#pragma unroll
  for (int i = 0; i < 4; ++i)
    cvt8_store(As0 + (((wave << 5) + (i << 3)) << 6) + awbase, a0[i], a1[i]);
  __syncthreads();

  u16 *asc = As0, *bsc = Bs0, *asn = As1, *bsn = Bs1;
  for (int k0 = 0; k0 < K; k0 += 64) {
    const bool more = (k0 + 64) < K;
    if (more) {
#pragma unroll
      for (int i = 0; i < 4; ++i) {
        const float* g = gAf + (size_t)(i << 3) * K + (k0 + 64);
        a0[i] = *(const float4*)g; a1[i] = *(const float4*)(g + 4);
      }
      stage_b(gB, bsn, wave, K, k0 + 64);   // B prefetch flies under MFMA
    }
    compute_step(asc, bsc, lane, wm, wn, acc);
    __syncthreads();                         // drains B gloads + A reg-loads
    if (more) {
#pragma unroll
      for (int i = 0; i < 4; ++i)
        cvt8_store(asn + (((wave << 5) + (i << 3)) << 6) + awbase, a0[i], a1[i]);
    }
    __syncthreads();                         // A writes visible to all waves
    u16* t_;
    t_ = asc; asc = asn; asn = t_;
    t_ = bsc; bsc = bsn; bsn = t_;
  }
  cwrite<0>(C, N, row0, col0, lane, wm, wn, acc);
}

// out projection (f32 out), 256 blocks, XCD-swizzled
template <int OUTF32>
__global__ __launch_bounds__(256, 2) void gemm_bt_kernel(
    const u16* __restrict__ A, const u16* __restrict__ Bt, void* __restrict__ C,
    int M, int N, int K)
{
  __shared__ u16 As[2][8192];
  __shared__ u16 Bs[2][8192];
  int bid = blockIdx.x;
  int t = (bid & 7) * 32 + (bid >> 3);      // bijective XCD chunk (256 = 8*32)
  const int bx = t & 7, by = t >> 3;
  gemm_core<OUTF32>(A, Bt, C, N, K, by << 7, bx << 7, As[0], As[1], Bs[0], Bs[1]);
}

// fused Q + K + V projections, f32 A direct (384 blocks), XCD-swizzled
__global__ __launch_bounds__(256, 2) void proj_kernel(
    const float* __restrict__ q, const float* __restrict__ k, const float* __restrict__ v,
    const u16* __restrict__ Wqt, const u16* __restrict__ Wkt, const u16* __restrict__ Wvt,
    u16* __restrict__ Qp, u16* __restrict__ KVp)
{
  __shared__ u16 As[2][8192];
  __shared__ u16 Bs[2][8192];
  int bid = blockIdx.x;
  int t = (bid & 7) * 48 + (bid >> 3);      // bijective XCD chunk (384 = 8*48)
  const float* Af; const u16* Bt; u16* C; int row0, col0;
  if (t < 256) {                            // Q projection: M=4096
    row0 = (t >> 3) << 7; col0 = (t & 7) << 7;
    Af = q + (size_t)row0 * 1024; Bt = Wqt; C = Qp;
  } else {                                  // K/V projections: M=2048
    int t2 = t - 256;
    row0 = (t2 >> 3) << 7; col0 = (t2 & 7) << 7;
    if (row0 < 1024) { Af = k + (size_t)row0 * 1024; Bt = Wkt; }
    else             { Af = v + (size_t)(row0 - 1024) * 1024; Bt = Wvt; }
    C = KVp;
  }
  gemm_core_f32a(Af, Bt, C, 1024, 1024, row0, col0, As[0], As[1], Bs[0], Bs[1]);
}

// ---------------- strided-local attention (MFMA) ------------------------------
#define VTP 56   // Vt pitch (elems)
#define PLP 72   // Pl pitch (elems)
__global__ __launch_bounds__(256) void attn_kernel(
    const u16* __restrict__ Qp, const u16* __restrict__ Kp,
    const u16* __restrict__ Vp, u16* __restrict__ Ob)
{
  __shared__ u16 Ql[64 * 64];          // swizzled 128B rows
  __shared__ u16 Kl[48 * 64];          // swizzled 128B rows
  __shared__ u16 Vt[64 * VTP + 64];    // V^T [d][c] + zeroed tail
  __shared__ u16 Pl[64 * PLP];         // P [jq][c], cols 48..63 zeroed

  const int jt = blockIdx.x, h = blockIdx.y, b = blockIdx.z;
  const int j0 = jt << 6;
  const int kbase = (j0 - 124) >> 2;
  const int tid = threadIdx.x;
  const int wave = tid >> 6, lane = tid & 63;

  const int srow = lane >> 3, sslot = lane & 7;
  const int scol = ((sslot ^ srow) << 3);
  for (int g = wave; g < 8; g += 4) {
    int r = (g << 3) + srow;
    const u16* ga = Qp + (((size_t)(b * 2048 + j0 + r)) << 10) + (h << 6) + scol;
    gload_lds16(ga, &Ql[g << 9]);
  }
  for (int g = wave; g < 6; g += 4) {
    int r = (g << 3) + srow;
    int key = kbase + r;
    key = key < 0 ? 0 : (key > 511 ? 511 : key);
    const u16* gk = Kp + (((size_t)(b * 512 + key)) << 10) + (h << 6) + scol;
    gload_lds16(gk, &Kl[g << 9]);
  }
  for (int idx = tid; idx < 48 * 8; idx += 256) {
    int row = idx >> 3, seg = idx & 7;
    int key = kbase + row;
    key = key < 0 ? 0 : (key > 511 ? 511 : key);
    uint4 x = *(const uint4*)(Vp + (((size_t)(b * 512 + key)) << 10) + (h << 6) + (seg << 3));
    int d0 = seg << 3;
    Vt[(d0 + 0) * VTP + row] = (u16)(x.x);
    Vt[(d0 + 1) * VTP + row] = (u16)(x.x >> 16);
    Vt[(d0 + 2) * VTP + row] = (u16)(x.y);
    Vt[(d0 + 3) * VTP + row] = (u16)(x.y >> 16);
    Vt[(d0 + 4) * VTP + row] = (u16)(x.z);
    Vt[(d0 + 5) * VTP + row] = (u16)(x.z >> 16);
    Vt[(d0 + 6) * VTP + row] = (u16)(x.w);
    Vt[(d0 + 7) * VTP + row] = (u16)(x.w >> 16);
  }
  if (tid < 64) *(uint4*)&Vt[tid * VTP + 48] = make_uint4(0, 0, 0, 0);
  else if (tid < 72) *(uint4*)&Vt[64 * VTP + ((tid - 64) << 3)] = make_uint4(0, 0, 0, 0);
  __syncthreads();

  f32x4 sacc[3] = {};
  const int frow_a = (wave << 4) + (lane & 15);
#pragma unroll
  for (int kk = 0; kk < 2; ++kk) {
    int colb = (kk << 6) + ((lane >> 4) << 4);
    bf16x8 aq = *(const bf16x8*)((const char*)Ql + (frow_a << 7) + (colb ^ ((frow_a & 7) << 4)));
#pragma unroll
    for (int nt = 0; nt < 3; ++nt) {
      int rk = (nt << 4) + (lane & 15);
      bf16x8 bk = *(const bf16x8*)((const char*)Kl + (rk << 7) + (colb ^ ((rk & 7) << 4)));
      sacc[nt] = __builtin_amdgcn_mfma_f32_16x16x32_bf16(aq, bk, sacc[nt], 0, 0, 0);
    }
  }

  const int rof = (wave << 2) + (lane >> 4);
  const int cb0 = lane & 15;
  bool vld[3]; float sc[3][4];
#pragma unroll
  for (int nt = 0; nt < 3; ++nt) {
    int c = cb0 + (nt << 4);
    vld[nt] = ((unsigned)(c - rof) < 32u) && (kbase + c >= 0);
#pragma unroll
    for (int r = 0; r < 4; ++r) sc[nt][r] = sacc[nt][r] * 0.125f;
  }
  float mx[4], rs[4];
#pragma unroll
  for (int r = 0; r < 4; ++r) {
    float m = -3.0e38f;
#pragma unroll
    for (int nt = 0; nt < 3; ++nt) m = vld[nt] ? fmaxf(m, sc[nt][r]) : m;
    m = fmaxf(m, __shfl_xor(m, 1));
    m = fmaxf(m, __shfl_xor(m, 2));
    m = fmaxf(m, __shfl_xor(m, 4));
    m = fmaxf(m, __shfl_xor(m, 8));
    mx[r] = m;
  }
#pragma unroll
  for (int r = 0; r < 4; ++r) {
    float s = 0.f;
#pragma unroll
    for (int nt = 0; nt < 3; ++nt) {
      float e = vld[nt] ? __expf(sc[nt][r] - mx[r]) : 0.f;
      sc[nt][r] = e;
      s += e;
    }
    s += __shfl_xor(s, 1);
    s += __shfl_xor(s, 2);
    s += __shfl_xor(s, 4);
    s += __shfl_xor(s, 8);
    rs[r] = 1.f / s;
  }
#pragma unroll
  for (int r = 0; r < 4; ++r) {
    int jq = (wave << 4) + ((lane >> 4) << 2) + r;
#pragma unroll
    for (int nt = 0; nt < 3; ++nt)
      Pl[jq * PLP + cb0 + (nt << 4)] = f2b(sc[nt][r] * rs[r]);
    Pl[jq * PLP + 48 + cb0] = 0;
  }
  __syncthreads();

  f32x4 oacc[4] = {};
#pragma unroll
  for (int kk = 0; kk < 2; ++kk) {
    int koff = (kk << 5) + ((lane >> 4) << 3);
    bf16x8 ap = *(const bf16x8*)&Pl[frow_a * PLP + koff];
#pragma unroll
    for (int nt = 0; nt < 4; ++nt) {
      int dr = (nt << 4) + (lane & 15);
      bf16x8 bv = *(const bf16x8*)&Vt[dr * VTP + koff];
      oacc[nt] = __builtin_amdgcn_mfma_f32_16x16x32_bf16(ap, bv, oacc[nt], 0, 0, 0);
    }
  }

#pragma unroll
  for (int nt = 0; nt < 4; ++nt) {
    int d = (nt << 4) + (lane & 15);
#pragma unroll
    for (int r = 0; r < 4; ++r) {
      int jq = (wave << 4) + ((lane >> 4) << 2) + r;
      Ob[(((size_t)(b * 2048 + j0 + jq)) << 10) + (h << 6) + d] = f2b(oacc[nt][r]);
    }
  }
}

extern "C" void kernel_launch(void* const* d_in, const int* in_sizes, int n_in,
                              void* d_out, int out_size, void* d_ws, size_t ws_size,
                              hipStream_t stream) {
  const float* q  = (const float*)d_in[0];
  const float* k  = (const float*)d_in[1];
  const float* v  = (const float*)d_in[2];
  const float* Wq = (const float*)d_in[3];
  const float* Wk = (const float*)d_in[4];
  const float* Wv = (const float*)d_in[5];
  const float* Wo = (const float*)d_in[6];

  char* ws = (char*)d_ws;
  const size_t MB = 1u << 20;
  u16* Wqt = (u16*)(ws + 0 * MB);    // 2 MB
  u16* Wkt = (u16*)(ws + 2 * MB);
  u16* Wvt = (u16*)(ws + 4 * MB);
  u16* Wot = (u16*)(ws + 6 * MB);
  u16* Qp  = (u16*)(ws + 8 * MB);    // 8 MB
  u16* Kp  = (u16*)(ws + 16 * MB);   // 2 MB  (Kp||Vp contiguous)
  u16* Vp  = (u16*)(ws + 18 * MB);   // 2 MB
  u16* Ob  = (u16*)(ws + 20 * MB);   // 8 MB  (total 28 MB)

  // 1) prep: transpose/convert the 4 weight matrices (weights only now)
  prep_kernel<<<4096, 256, 0, stream>>>(Wq, Wk, Wv, Wo, Wqt, Wkt, Wvt, Wot);
  // 2) all three projections, f32 A read directly + reg-staged cvt
  proj_kernel<<<384, 256, 0, stream>>>(q, k, v, Wqt, Wkt, Wvt, Qp, Kp);
  // 3) attention (MFMA)
  attn_kernel<<<dim3(32, 16, 2), 256, 0, stream>>>(Qp, Kp, Vp, Ob);
  // 4) output projection (f32 out)
  gemm_bt_kernel<1><<<256, 256, 0, stream>>>(Ob, Wot, d_out, 4096, 1024, 1024);
}